// Round 11
// baseline (523.451 us; speedup 1.0000x reference)
//
#include <hip/hip_runtime.h>
#include <hip/hip_bf16.h>

#define PTOT   32768
#define KNB    16
#define NCLOUD 16
#define OUTC   512
#define A1S    168   // sa2 A1 row stride in ushort (336 B, 16B-aligned)
#define A2S    264   // sa2 A2 row stride in ushort (528 B, 16B-aligned)
#define TTIL   4     // point-tiles (of 8 points) per sa2 block

typedef __attribute__((ext_vector_type(8)))  short v8bf;
typedef __attribute__((ext_vector_type(16))) float v16f;

__device__ __forceinline__ unsigned short f2b(float v) {
    __hip_bfloat16 h = __float2bfloat16(v);
    return *reinterpret_cast<unsigned short*>(&h);
}
__device__ __forceinline__ unsigned fenc(float f) {
    unsigned u = __float_as_uint(f);
    return (u & 0x80000000u) ? ~u : (u | 0x80000000u);
}
__device__ __forceinline__ float fdec(unsigned u) {
    unsigned b = (u & 0x80000000u) ? (u & 0x7FFFFFFFu) : ~u;
    return __uint_as_float(b);
}
__device__ __forceinline__ v16f zero16() {
    v16f z;
    #pragma unroll
    for (int i = 0; i < 16; ++i) z[i] = 0.0f;
    return z;
}

// ======= prep: k-major bf16 fragment images of W3, W4, W1 (pad K 3->16), W2;
//         also zero-inits encbuf =============================================
__global__ void prep_kernel(const float* __restrict__ W1, const float* __restrict__ W2,
                            const float* __restrict__ W3, const float* __restrict__ W4,
                            unsigned short* __restrict__ W1s, unsigned short* __restrict__ W2s,
                            unsigned short* __restrict__ W3s, unsigned short* __restrict__ W4s,
                            unsigned* __restrict__ encbuf)
{
    int i = blockIdx.x * 256 + threadIdx.x;
    if (i < NCLOUD * OUTC) encbuf[i] = 0u;   // fenc-domain -inf
    if (i < 40960) {                         // W3s[(c2*256+n)*8+j] = W3[c2*8+j][n]
        int j = i & 7, n = (i >> 3) & 255, c2 = i >> 11;
        int k = c2 * 8 + j;
        W3s[i] = f2b(k < 131 ? W3[k * 256 + n] : 0.0f);
    }
    int i2 = i - 40960;
    if (i2 >= 0 && i2 < 131072) {            // W4s[(c2*512+n)*8+j] = W4[c2*8+j][n]
        int j = i2 & 7, n = (i2 >> 3) & 511, c2 = i2 >> 12;
        int k = c2 * 8 + j;
        W4s[i2] = f2b(W4[k * 512 + n]);
    }
    int i3 = i - 172032;
    if (i3 >= 0 && i3 < 1024) {              // W1s[n*16+k] = W1[k][n] (k<3) else 0
        int k = i3 & 15, n = i3 >> 4;
        W1s[i3] = f2b(k < 3 ? W1[k * 64 + n] : 0.0f);
    }
    int i4 = i - 173056;
    if (i4 >= 0 && i4 < 8192) {              // W2s[n*64+k] = W2[k][n]
        int k = i4 & 63, n = i4 >> 6;
        W2s[i4] = f2b(W2[k * 128 + n]);
    }
}

// ======= sa1 (MFMA): R8-proven — block = 4 points (M=64), 256 thr ===========
__global__ __launch_bounds__(256) void sa1_kernel(
    const float* __restrict__ pos, const int* __restrict__ nbr,
    const unsigned short* __restrict__ W1s, const float* __restrict__ b1,
    const unsigned short* __restrict__ W2s, const float* __restrict__ b2,
    unsigned short* __restrict__ x1b)
{
    __shared__ unsigned short A1d[64 * 16];   // 2 KB
    __shared__ unsigned short A2[64 * 72];    // 9 KB
    const int tid  = threadIdx.x;
    const int lane = tid & 63;
    const int wave = tid >> 6;
    const int l31  = lane & 31;
    const int h    = lane >> 5;
    const int p0   = blockIdx.x * 4;

    if (tid < 64) {
        int r = tid;
        int j = nbr[p0 * KNB + r];
        int p = p0 + (r >> 4);
        v8bf z;
        #pragma unroll
        for (int i = 0; i < 8; ++i) z[i] = 0;
        v8bf dv = z;
        dv[0] = (short)f2b(pos[j * 3 + 0] - pos[p * 3 + 0]);
        dv[1] = (short)f2b(pos[j * 3 + 1] - pos[p * 3 + 1]);
        dv[2] = (short)f2b(pos[j * 3 + 2] - pos[p * 3 + 2]);
        *(v8bf*)(A1d + r * 16)     = dv;
        *(v8bf*)(A1d + r * 16 + 8) = z;
    }
    const int c1 = (wave >> 1) * 32 + l31;
    v8bf b1f = *(const v8bf*)(W1s + c1 * 16 + h * 8);
    const float b1v = b1[c1];
    __syncthreads();

    {
        v8bf a = *(const v8bf*)(A1d + ((wave & 1) * 32 + l31) * 16 + h * 8);
        v16f acc = __builtin_amdgcn_mfma_f32_32x32x16_bf16(a, b1f, zero16(), 0, 0, 0);
        #pragma unroll
        for (int r = 0; r < 16; ++r) {
            int row = (wave & 1) * 32 + (r & 3) + 8 * (r >> 2) + 4 * h;
            A2[row * 72 + c1] = f2b(fmaxf(acc[r] + b1v, 0.0f));
        }
    }
    v8bf B2[4];
    #pragma unroll
    for (int kc = 0; kc < 4; ++kc)
        B2[kc] = *(const v8bf*)(W2s + (wave * 32 + l31) * 64 + kc * 16 + h * 8);
    const float b2v = b2[wave * 32 + l31];
    __syncthreads();

    #pragma unroll
    for (int rt = 0; rt < 2; ++rt) {
        v16f acc = zero16();
        #pragma unroll
        for (int kc = 0; kc < 4; ++kc) {
            v8bf a = *(const v8bf*)(A2 + (rt * 32 + l31) * 72 + kc * 16 + h * 8);
            acc = __builtin_amdgcn_mfma_f32_32x32x16_bf16(a, B2[kc], acc, 0, 0, 0);
        }
        float ma = acc[0], mb = acc[8];
        #pragma unroll
        for (int r = 1; r < 8; ++r) { ma = fmaxf(ma, acc[r]); mb = fmaxf(mb, acc[8 + r]); }
        ma = fmaxf(ma, __shfl_xor(ma, 32));
        mb = fmaxf(mb, __shfl_xor(mb, 32));
        int p = p0 + rt * 2 + h;
        float m = h ? mb : ma;
        x1b[p * 128 + wave * 32 + l31] = f2b(m + b2v);
    }
}

// ==== sa2: persistent-B multi-tile. 512 thr, T=4 tiles of 8 points.
// Wave owns 2 of 16 G2 col-tiles (B2 in 128 regs, loaded once) and 1 of 8 G1
// col-tiles. Separate A1/A2 LDS; A1(t+1) prefetched during G2(t). ===========
__global__ __launch_bounds__(512) void sa2_kernel(
    const float* __restrict__ pos, const int* __restrict__ nbr,
    const int* __restrict__ batch,
    const unsigned short* __restrict__ W3s, const float* __restrict__ b3,
    const unsigned short* __restrict__ W4s, const float* __restrict__ b4,
    const unsigned short* __restrict__ x1b, unsigned* __restrict__ encbuf)
{
    __shared__ unsigned short A1[128 * A1S];   // 43008 B
    __shared__ unsigned short A2[128 * A2S];   // 67584 B (total 110592 < 160K)
    const int tid  = threadIdx.x;
    const int lane = tid & 63;
    const int wave = tid >> 6;     // 0..7
    const int l31  = lane & 31;
    const int h    = lane >> 5;
    const int pbase = blockIdx.x * (8 * TTIL);

    // ---- persistent GEMM2 B-fragments: wave's 2 col-tiles, read ONCE per block
    const int n0 = (wave * 2 + 0) * 32 + l31;
    const int n1 = (wave * 2 + 1) * 32 + l31;
    v8bf B2a[16], B2b[16];
    #pragma unroll
    for (int kc = 0; kc < 16; ++kc) {
        int c2 = kc * 2 + h;
        B2a[kc] = *(const v8bf*)(W4s + ((c2 * 512 + n0) << 3));
        B2b[kc] = *(const v8bf*)(W4s + ((c2 * 512 + n1) << 3));
    }
    const int cw = wave * 32 + l31;    // G1 col (wave owns 1 of 8 col-tiles)
    const float b3v = b3[cw];

    float rm0 = -3.4e38f, rm1 = -3.4e38f;
    const int rs = tid >> 2, q4 = tid & 3;   // staging: 4 threads/row

    // ---- stage tile 0 into A1
    {
        int j = nbr[pbase * KNB + rs];
        const uint4* src = (const uint4*)(x1b + j * 128 + q4 * 32);
        uint4* dst = (uint4*)(A1 + rs * A1S + q4 * 32);
        dst[0] = src[0]; dst[1] = src[1]; dst[2] = src[2]; dst[3] = src[3];
        if (tid < 128) {
            int jj = nbr[pbase * KNB + tid];
            int pp = pbase + (tid >> 4);
            v8bf z;
            #pragma unroll
            for (int i = 0; i < 8; ++i) z[i] = 0;
            v8bf dv = z;
            dv[0] = (short)f2b(pos[jj * 3 + 0] - pos[pp * 3 + 0]);
            dv[1] = (short)f2b(pos[jj * 3 + 1] - pos[pp * 3 + 1]);
            dv[2] = (short)f2b(pos[jj * 3 + 2] - pos[pp * 3 + 2]);
            *(v8bf*)(A1 + tid * A1S + 128) = dv;
            *(v8bf*)(A1 + tid * A1S + 136) = z;
        }
    }
    __syncthreads();

    for (int t = 0; t < TTIL; ++t) {
        // ---- G1: wave's col-tile over 4 row-tiles; B1 reloaded per tile (L2-hot)
        v8bf B1[9];
        #pragma unroll
        for (int kc = 0; kc < 9; ++kc) {
            int c2 = kc * 2 + h;
            B1[kc] = *(const v8bf*)(W3s + ((c2 * 256 + cw) << 3));
        }
        #pragma unroll
        for (int rt = 0; rt < 4; ++rt) {
            v16f g = zero16();
            #pragma unroll
            for (int kc = 0; kc < 9; ++kc) {
                v8bf a = *(const v8bf*)(A1 + (rt * 32 + l31) * A1S + kc * 16 + h * 8);
                g = __builtin_amdgcn_mfma_f32_32x32x16_bf16(a, B1[kc], g, 0, 0, 0);
            }
            #pragma unroll
            for (int i = 0; i < 16; ++i) {
                int row = rt * 32 + (i & 3) + 8 * (i >> 2) + 4 * h;
                A2[row * A2S + cw] = f2b(fmaxf(g[i] + b3v, 0.0f));
            }
        }
        __syncthreads();   // A2 ready; A1 reads done (A1 free for prefetch writes)

        // ---- prefetch tile t+1 gather into registers (latency hides under G2)
        uint4 pv0, pv1, pv2, pv3;
        float dx = 0.f, dy = 0.f, dz = 0.f;
        const int have = (t + 1 < TTIL);
        if (have) {
            int p0n = pbase + (t + 1) * 8;
            int j = nbr[p0n * KNB + rs];
            const uint4* src = (const uint4*)(x1b + j * 128 + q4 * 32);
            pv0 = src[0]; pv1 = src[1]; pv2 = src[2]; pv3 = src[3];
            if (tid < 128) {
                int jj = nbr[p0n * KNB + tid];
                int pp = p0n + (tid >> 4);
                dx = pos[jj * 3 + 0] - pos[pp * 3 + 0];
                dy = pos[jj * 3 + 1] - pos[pp * 3 + 1];
                dz = pos[jj * 3 + 2] - pos[pp * 3 + 2];
            }
        }

        // ---- G2: wave's 2 col-tiles over 4 row-tiles; B2 from registers
        #pragma unroll
        for (int rt = 0; rt < 4; ++rt) {
            v16f a0 = zero16(), a1 = zero16();
            #pragma unroll
            for (int kc = 0; kc < 16; ++kc) {
                v8bf a = *(const v8bf*)(A2 + (rt * 32 + l31) * A2S + kc * 16 + h * 8);
                a0 = __builtin_amdgcn_mfma_f32_32x32x16_bf16(a, B2a[kc], a0, 0, 0, 0);
                a1 = __builtin_amdgcn_mfma_f32_32x32x16_bf16(a, B2b[kc], a1, 0, 0, 0);
            }
            #pragma unroll
            for (int r = 0; r < 16; ++r) {
                rm0 = fmaxf(rm0, a0[r]);
                rm1 = fmaxf(rm1, a1[r]);
            }
        }

        // ---- write prefetched staging into A1 for tile t+1
        if (have) {
            uint4* dst = (uint4*)(A1 + rs * A1S + q4 * 32);
            dst[0] = pv0; dst[1] = pv1; dst[2] = pv2; dst[3] = pv3;
            if (tid < 128) {
                v8bf z;
                #pragma unroll
                for (int i = 0; i < 8; ++i) z[i] = 0;
                v8bf dv = z;
                dv[0] = (short)f2b(dx);
                dv[1] = (short)f2b(dy);
                dv[2] = (short)f2b(dz);
                *(v8bf*)(A1 + tid * A1S + 128) = dv;
                *(v8bf*)(A1 + tid * A1S + 136) = z;
            }
        }
        __syncthreads();   // A2 reads + A1 staging writes complete
    }

    // ---- epilogue: fold half-waves, add bias, one atomic pair per wave
    rm0 = fmaxf(rm0, __shfl_xor(rm0, 32));
    rm1 = fmaxf(rm1, __shfl_xor(rm1, 32));
    rm0 += b4[n0];
    rm1 += b4[n1];
    const int cloud = batch[pbase];
    if (lane < 32) {
        atomicMax(&encbuf[cloud * OUTC + n0], fenc(rm0));
        atomicMax(&encbuf[cloud * OUTC + n1], fenc(rm1));
    }
}

// ============================ finalize: decode encoded maxima ================
__global__ void finalize_kernel(const unsigned* __restrict__ encv,
                                float* __restrict__ out)
{
    int i = blockIdx.x * 256 + threadIdx.x;
    if (i < NCLOUD * OUTC) out[i] = fdec(encv[i]);
}

extern "C" void kernel_launch(void* const* d_in, const int* in_sizes, int n_in,
                              void* d_out, int out_size, void* d_ws, size_t ws_size,
                              hipStream_t stream)
{
    const float* pos   = (const float*)d_in[0];
    const int*   nbr   = (const int*)  d_in[1];
    const int*   batch = (const int*)  d_in[2];
    const float* W1    = (const float*)d_in[3];
    const float* b1    = (const float*)d_in[4];
    const float* W2    = (const float*)d_in[5];
    const float* b2    = (const float*)d_in[6];
    const float* W3    = (const float*)d_in[7];
    const float* b3    = (const float*)d_in[8];
    const float* W4    = (const float*)d_in[9];
    const float* b4    = (const float*)d_in[10];

    unsigned short* x1b = (unsigned short*)d_ws;                          // 8 MB
    unsigned short* W3s = (unsigned short*)((char*)d_ws + 8388608);       // 80 KB
    unsigned short* W4s = (unsigned short*)((char*)d_ws + 8470528);       // 256 KB
    unsigned*    encbuf = (unsigned*)((char*)d_ws + 8732672);             // 32 KB
    unsigned short* W1s = (unsigned short*)((char*)d_ws + 8765440);       // 2 KB
    unsigned short* W2s = (unsigned short*)((char*)d_ws + 8767488);       // 16 KB

    prep_kernel<<<708, 256, 0, stream>>>(W1, W2, W3, W4, W1s, W2s, W3s, W4s, encbuf);
    sa1_kernel<<<PTOT / 4, 256, 0, stream>>>(pos, nbr, W1s, b1, W2s, b2, x1b);
    sa2_kernel<<<PTOT / (8 * TTIL), 512, 0, stream>>>(pos, nbr, batch, W3s, b3, W4s, b4, x1b, encbuf);
    finalize_kernel<<<(NCLOUD * OUTC + 255) / 256, 256, 0, stream>>>(encbuf, (float*)d_out);
}

// Round 12
// 286.590 us; speedup vs baseline: 1.8265x; 1.8265x over previous
//
#include <hip/hip_runtime.h>
#include <hip/hip_bf16.h>

#define PTOT   32768
#define KNB    16
#define NCLOUD 16
#define OUTC   512
#define A1S    168   // sa2 A1 row stride in ushort (336 B, 16B-aligned)
#define A2S    264   // sa2 A2 row stride in ushort (528 B, 16B-aligned)

typedef __attribute__((ext_vector_type(8)))  short v8bf;
typedef __attribute__((ext_vector_type(16))) float v16f;

__device__ __forceinline__ unsigned short f2b(float v) {
    __hip_bfloat16 h = __float2bfloat16(v);
    return *reinterpret_cast<unsigned short*>(&h);
}
__device__ __forceinline__ unsigned pk2(float a, float b) {
    return (unsigned)f2b(a) | ((unsigned)f2b(b) << 16);
}
__device__ __forceinline__ unsigned fenc(float f) {
    unsigned u = __float_as_uint(f);
    return (u & 0x80000000u) ? ~u : (u | 0x80000000u);
}
__device__ __forceinline__ float fdec(unsigned u) {
    unsigned b = (u & 0x80000000u) ? (u & 0x7FFFFFFFu) : ~u;
    return __uint_as_float(b);
}
__device__ __forceinline__ v16f zero16() {
    v16f z;
    #pragma unroll
    for (int i = 0; i < 16; ++i) z[i] = 0.0f;
    return z;
}

// ======= prep: k-major bf16 fragment images of W3, W4, W1 (pad K 3->16), W2;
//         also zero-inits encbuf =============================================
__global__ void prep_kernel(const float* __restrict__ W1, const float* __restrict__ W2,
                            const float* __restrict__ W3, const float* __restrict__ W4,
                            unsigned short* __restrict__ W1s, unsigned short* __restrict__ W2s,
                            unsigned short* __restrict__ W3s, unsigned short* __restrict__ W4s,
                            unsigned* __restrict__ encbuf)
{
    int i = blockIdx.x * 256 + threadIdx.x;
    if (i < NCLOUD * OUTC) encbuf[i] = 0u;   // fenc-domain -inf
    if (i < 40960) {                         // W3s[(c2*256+n)*8+j] = W3[c2*8+j][n]
        int j = i & 7, n = (i >> 3) & 255, c2 = i >> 11;
        int k = c2 * 8 + j;
        W3s[i] = f2b(k < 131 ? W3[k * 256 + n] : 0.0f);
    }
    int i2 = i - 40960;
    if (i2 >= 0 && i2 < 131072) {            // W4s[(c2*512+n)*8+j] = W4[c2*8+j][n]
        int j = i2 & 7, n = (i2 >> 3) & 511, c2 = i2 >> 12;
        int k = c2 * 8 + j;
        W4s[i2] = f2b(W4[k * 512 + n]);
    }
    int i3 = i - 172032;
    if (i3 >= 0 && i3 < 1024) {              // W1s[n*16+k] = W1[k][n] (k<3) else 0
        int k = i3 & 15, n = i3 >> 4;
        W1s[i3] = f2b(k < 3 ? W1[k * 64 + n] : 0.0f);
    }
    int i4 = i - 173056;
    if (i4 >= 0 && i4 < 8192) {              // W2s[n*64+k] = W2[k][n]
        int k = i4 & 63, n = i4 >> 6;
        W2s[i4] = f2b(W2[k * 128 + n]);
    }
}

// ======= sa1 (MFMA): R8-proven — block = 4 points (M=64), 256 thr ===========
__global__ __launch_bounds__(256) void sa1_kernel(
    const float* __restrict__ pos, const int* __restrict__ nbr,
    const unsigned short* __restrict__ W1s, const float* __restrict__ b1,
    const unsigned short* __restrict__ W2s, const float* __restrict__ b2,
    unsigned short* __restrict__ x1b)
{
    __shared__ unsigned short A1d[64 * 16];   // 2 KB
    __shared__ unsigned short A2[64 * 72];    // 9 KB
    const int tid  = threadIdx.x;
    const int lane = tid & 63;
    const int wave = tid >> 6;
    const int l31  = lane & 31;
    const int h    = lane >> 5;
    const int p0   = blockIdx.x * 4;

    if (tid < 64) {
        int r = tid;
        int j = nbr[p0 * KNB + r];
        int p = p0 + (r >> 4);
        v8bf z;
        #pragma unroll
        for (int i = 0; i < 8; ++i) z[i] = 0;
        v8bf dv = z;
        dv[0] = (short)f2b(pos[j * 3 + 0] - pos[p * 3 + 0]);
        dv[1] = (short)f2b(pos[j * 3 + 1] - pos[p * 3 + 1]);
        dv[2] = (short)f2b(pos[j * 3 + 2] - pos[p * 3 + 2]);
        *(v8bf*)(A1d + r * 16)     = dv;
        *(v8bf*)(A1d + r * 16 + 8) = z;
    }
    const int c1 = (wave >> 1) * 32 + l31;
    v8bf b1f = *(const v8bf*)(W1s + c1 * 16 + h * 8);
    const float b1v = b1[c1];
    __syncthreads();

    {
        v8bf a = *(const v8bf*)(A1d + ((wave & 1) * 32 + l31) * 16 + h * 8);
        v16f acc = __builtin_amdgcn_mfma_f32_32x32x16_bf16(a, b1f, zero16(), 0, 0, 0);
        #pragma unroll
        for (int r = 0; r < 16; ++r) {
            int row = (wave & 1) * 32 + (r & 3) + 8 * (r >> 2) + 4 * h;
            A2[row * 72 + c1] = f2b(fmaxf(acc[r] + b1v, 0.0f));
        }
    }
    v8bf B2[4];
    #pragma unroll
    for (int kc = 0; kc < 4; ++kc)
        B2[kc] = *(const v8bf*)(W2s + (wave * 32 + l31) * 64 + kc * 16 + h * 8);
    const float b2v = b2[wave * 32 + l31];
    __syncthreads();

    #pragma unroll
    for (int rt = 0; rt < 2; ++rt) {
        v16f acc = zero16();
        #pragma unroll
        for (int kc = 0; kc < 4; ++kc) {
            v8bf a = *(const v8bf*)(A2 + (rt * 32 + l31) * 72 + kc * 16 + h * 8);
            acc = __builtin_amdgcn_mfma_f32_32x32x16_bf16(a, B2[kc], acc, 0, 0, 0);
        }
        float ma = acc[0], mb = acc[8];
        #pragma unroll
        for (int r = 1; r < 8; ++r) { ma = fmaxf(ma, acc[r]); mb = fmaxf(mb, acc[8 + r]); }
        ma = fmaxf(ma, __shfl_xor(ma, 32));
        mb = fmaxf(mb, __shfl_xor(mb, 32));
        int p = p0 + rt * 2 + h;
        float m = h ? mb : ma;
        x1b[p * 128 + wave * 32 + l31] = f2b(m + b2v);
    }
}

// ==== sa2: (4,4) acc tiling — 256 thr, 4 waves, M=128, big register budget ==
// launch_bounds(256,1): 1 wave/EU -> up to 512 regs/wave, no spill.
// G1: wave owns 2 of 8 col-tiles, kc-outer (W3s read once/block), 8 accs.
// G2: wave owns 4 of 16 col-tiles, kc-outer (W4s once, A-reads halved), 16 accs.
__global__ __launch_bounds__(256, 1) void sa2_kernel(
    const float* __restrict__ pos, const int* __restrict__ nbr,
    const int* __restrict__ batch,
    const unsigned short* __restrict__ W3s, const float* __restrict__ b3,
    const unsigned short* __restrict__ W4s, const float* __restrict__ b4,
    const unsigned short* __restrict__ x1b, unsigned* __restrict__ encbuf)
{
    __shared__ unsigned short S[128 * A2S];   // 67584 B: A1 (stride A1S) overlaid, then A2
    const int tid  = threadIdx.x;
    const int lane = tid & 63;
    const int wave = tid >> 6;     // 0..3
    const int l31  = lane & 31;
    const int h    = lane >> 5;
    const int p0   = blockIdx.x * 8;

    // ---- stage A1: 128 rows = (point, nbr); 2 threads/row, 128 B each
    {
        int r = tid >> 1, q = tid & 1;
        int j = nbr[p0 * KNB + r];
        const uint4* src = (const uint4*)(x1b + j * 128 + q * 64);
        uint4* dst = (uint4*)(S + r * A1S + q * 64);
        #pragma unroll
        for (int i = 0; i < 8; ++i) dst[i] = src[i];
    }
    if (tid < 128) {
        int r = tid;
        int j = nbr[p0 * KNB + r];
        int p = p0 + (r >> 4);
        v8bf z;
        #pragma unroll
        for (int i = 0; i < 8; ++i) z[i] = 0;
        v8bf dv = z;
        dv[0] = (short)f2b(pos[j * 3 + 0] - pos[p * 3 + 0]);
        dv[1] = (short)f2b(pos[j * 3 + 1] - pos[p * 3 + 1]);
        dv[2] = (short)f2b(pos[j * 3 + 2] - pos[p * 3 + 2]);
        *(v8bf*)(S + r * A1S + 128) = dv;
        *(v8bf*)(S + r * A1S + 136) = z;
    }
    __syncthreads();

    // ---- GEMM1: wave's 2 col-tiles x 4 row-tiles, kc-outer, B streamed once
    // kc=9 (k=144..159) all-zero pad -> skipped.
    const int n1a = (wave * 2 + 0) * 32 + l31;
    const int n1b = (wave * 2 + 1) * 32 + l31;
    v16f g[4][2];
    #pragma unroll
    for (int rt = 0; rt < 4; ++rt) { g[rt][0] = zero16(); g[rt][1] = zero16(); }
    #pragma unroll
    for (int kc = 0; kc < 9; ++kc) {
        int c2 = kc * 2 + h;
        v8bf B0 = *(const v8bf*)(W3s + ((c2 * 256 + n1a) << 3));
        v8bf B1 = *(const v8bf*)(W3s + ((c2 * 256 + n1b) << 3));
        #pragma unroll
        for (int rt = 0; rt < 4; ++rt) {
            v8bf a = *(const v8bf*)(S + (rt * 32 + l31) * A1S + kc * 16 + h * 8);
            g[rt][0] = __builtin_amdgcn_mfma_f32_32x32x16_bf16(a, B0, g[rt][0], 0, 0, 0);
            g[rt][1] = __builtin_amdgcn_mfma_f32_32x32x16_bf16(a, B1, g[rt][1], 0, 0, 0);
        }
    }
    const float b3v0 = b3[n1a];
    const float b3v1 = b3[n1b];
    unsigned st[4][2][8];
    #pragma unroll
    for (int rt = 0; rt < 4; ++rt) {
        #pragma unroll
        for (int i = 0; i < 8; ++i) {
            st[rt][0][i] = pk2(fmaxf(g[rt][0][2*i] + b3v0, 0.0f), fmaxf(g[rt][0][2*i+1] + b3v0, 0.0f));
            st[rt][1][i] = pk2(fmaxf(g[rt][1][2*i] + b3v1, 0.0f), fmaxf(g[rt][1][2*i+1] + b3v1, 0.0f));
        }
    }
    __syncthreads();   // all A1 reads complete — safe to overwrite with A2

    // ---- store A2 = bf16(relu(GEMM1)) row-major, stride A2S
    #pragma unroll
    for (int rt = 0; rt < 4; ++rt) {
        #pragma unroll
        for (int i = 0; i < 8; ++i) {
            int row = rt * 32 + ((2*i) & 3) + 8 * ((2*i) >> 2) + 4 * h;
            S[row * A2S + n1a]       = (unsigned short)(st[rt][0][i] & 0xFFFF);
            S[(row + 1) * A2S + n1a] = (unsigned short)(st[rt][0][i] >> 16);
            S[row * A2S + n1b]       = (unsigned short)(st[rt][1][i] & 0xFFFF);
            S[(row + 1) * A2S + n1b] = (unsigned short)(st[rt][1][i] >> 16);
        }
    }
    __syncthreads();   // A2 ready

    // ---- GEMM2: wave's 4 col-tiles x 4 row-tiles, kc-outer, 16 accs
    const int nc0 = (wave * 4 + 0) * 32 + l31;
    const int nc1 = (wave * 4 + 1) * 32 + l31;
    const int nc2 = (wave * 4 + 2) * 32 + l31;
    const int nc3 = (wave * 4 + 3) * 32 + l31;
    v16f acc[4][4];
    #pragma unroll
    for (int rt = 0; rt < 4; ++rt)
        #pragma unroll
        for (int c = 0; c < 4; ++c) acc[rt][c] = zero16();
    #pragma unroll
    for (int kc = 0; kc < 16; ++kc) {
        int c2 = kc * 2 + h;
        v8bf B0 = *(const v8bf*)(W4s + ((c2 * 512 + nc0) << 3));
        v8bf B1 = *(const v8bf*)(W4s + ((c2 * 512 + nc1) << 3));
        v8bf B2 = *(const v8bf*)(W4s + ((c2 * 512 + nc2) << 3));
        v8bf B3 = *(const v8bf*)(W4s + ((c2 * 512 + nc3) << 3));
        #pragma unroll
        for (int rt = 0; rt < 4; ++rt) {
            v8bf a = *(const v8bf*)(S + (rt * 32 + l31) * A2S + kc * 16 + h * 8);
            acc[rt][0] = __builtin_amdgcn_mfma_f32_32x32x16_bf16(a, B0, acc[rt][0], 0, 0, 0);
            acc[rt][1] = __builtin_amdgcn_mfma_f32_32x32x16_bf16(a, B1, acc[rt][1], 0, 0, 0);
            acc[rt][2] = __builtin_amdgcn_mfma_f32_32x32x16_bf16(a, B2, acc[rt][2], 0, 0, 0);
            acc[rt][3] = __builtin_amdgcn_mfma_f32_32x32x16_bf16(a, B3, acc[rt][3], 0, 0, 0);
        }
    }

    // ---- epilogue: per-col max over all rows, fold halves, bias, atomics
    float rm[4];
    #pragma unroll
    for (int c = 0; c < 4; ++c) {
        float m = acc[0][c][0];
        #pragma unroll
        for (int rt = 0; rt < 4; ++rt)
            #pragma unroll
            for (int r = 0; r < 16; ++r) m = fmaxf(m, acc[rt][c][r]);
        rm[c] = fmaxf(m, __shfl_xor(m, 32));
    }
    const int cloud = batch[p0];
    rm[0] += b4[nc0]; rm[1] += b4[nc1]; rm[2] += b4[nc2]; rm[3] += b4[nc3];
    if (lane < 32) {
        atomicMax(&encbuf[cloud * OUTC + nc0], fenc(rm[0]));
        atomicMax(&encbuf[cloud * OUTC + nc1], fenc(rm[1]));
        atomicMax(&encbuf[cloud * OUTC + nc2], fenc(rm[2]));
        atomicMax(&encbuf[cloud * OUTC + nc3], fenc(rm[3]));
    }
}

// ============================ finalize: decode encoded maxima ================
__global__ void finalize_kernel(const unsigned* __restrict__ encv,
                                float* __restrict__ out)
{
    int i = blockIdx.x * 256 + threadIdx.x;
    if (i < NCLOUD * OUTC) out[i] = fdec(encv[i]);
}

extern "C" void kernel_launch(void* const* d_in, const int* in_sizes, int n_in,
                              void* d_out, int out_size, void* d_ws, size_t ws_size,
                              hipStream_t stream)
{
    const float* pos   = (const float*)d_in[0];
    const int*   nbr   = (const int*)  d_in[1];
    const int*   batch = (const int*)  d_in[2];
    const float* W1    = (const float*)d_in[3];
    const float* b1    = (const float*)d_in[4];
    const float* W2    = (const float*)d_in[5];
    const float* b2    = (const float*)d_in[6];
    const float* W3    = (const float*)d_in[7];
    const float* b3    = (const float*)d_in[8];
    const float* W4    = (const float*)d_in[9];
    const float* b4    = (const float*)d_in[10];

    unsigned short* x1b = (unsigned short*)d_ws;                          // 8 MB
    unsigned short* W3s = (unsigned short*)((char*)d_ws + 8388608);       // 80 KB
    unsigned short* W4s = (unsigned short*)((char*)d_ws + 8470528);       // 256 KB
    unsigned*    encbuf = (unsigned*)((char*)d_ws + 8732672);             // 32 KB
    unsigned short* W1s = (unsigned short*)((char*)d_ws + 8765440);       // 2 KB
    unsigned short* W2s = (unsigned short*)((char*)d_ws + 8767488);       // 16 KB

    prep_kernel<<<708, 256, 0, stream>>>(W1, W2, W3, W4, W1s, W2s, W3s, W4s, encbuf);
    sa1_kernel<<<PTOT / 4, 256, 0, stream>>>(pos, nbr, W1s, b1, W2s, b2, x1b);
    sa2_kernel<<<PTOT / 8, 256, 0, stream>>>(pos, nbr, batch, W3s, b3, W4s, b4, x1b, encbuf);
    finalize_kernel<<<(NCLOUD * OUTC + 255) / 256, 256, 0, stream>>>(encbuf, (float*)d_out);
}

// Round 13
// 250.388 us; speedup vs baseline: 2.0906x; 1.1446x over previous
//
#include <hip/hip_runtime.h>
#include <hip/hip_bf16.h>

#define PTOT   32768
#define KNB    16
#define NCLOUD 16
#define OUTC   512
#define A1S    168   // sa2 A1 row stride in ushort (336 B, 16B-aligned)
#define A2S    264   // sa2 A2 row stride in ushort (528 B, 16B-aligned)

typedef __attribute__((ext_vector_type(8)))  short v8bf;
typedef __attribute__((ext_vector_type(16))) float v16f;

__device__ __forceinline__ unsigned short f2b(float v) {
    __hip_bfloat16 h = __float2bfloat16(v);
    return *reinterpret_cast<unsigned short*>(&h);
}
__device__ __forceinline__ unsigned pk2(float a, float b) {
    return (unsigned)f2b(a) | ((unsigned)f2b(b) << 16);
}
__device__ __forceinline__ unsigned fenc(float f) {
    unsigned u = __float_as_uint(f);
    return (u & 0x80000000u) ? ~u : (u | 0x80000000u);
}
__device__ __forceinline__ float fdec(unsigned u) {
    unsigned b = (u & 0x80000000u) ? (u & 0x7FFFFFFFu) : ~u;
    return __uint_as_float(b);
}
__device__ __forceinline__ v16f zero16() {
    v16f z;
    #pragma unroll
    for (int i = 0; i < 16; ++i) z[i] = 0.0f;
    return z;
}

// ======= prep: k-major bf16 fragment images of W3, W4, W1 (pad K 3->16), W2;
//         also zero-inits encbuf =============================================
__global__ void prep_kernel(const float* __restrict__ W1, const float* __restrict__ W2,
                            const float* __restrict__ W3, const float* __restrict__ W4,
                            unsigned short* __restrict__ W1s, unsigned short* __restrict__ W2s,
                            unsigned short* __restrict__ W3s, unsigned short* __restrict__ W4s,
                            unsigned* __restrict__ encbuf)
{
    int i = blockIdx.x * 256 + threadIdx.x;
    if (i < NCLOUD * OUTC) encbuf[i] = 0u;   // fenc-domain -inf
    if (i < 40960) {                         // W3s[(c2*256+n)*8+j] = W3[c2*8+j][n]
        int j = i & 7, n = (i >> 3) & 255, c2 = i >> 11;
        int k = c2 * 8 + j;
        W3s[i] = f2b(k < 131 ? W3[k * 256 + n] : 0.0f);
    }
    int i2 = i - 40960;
    if (i2 >= 0 && i2 < 131072) {            // W4s[(c2*512+n)*8+j] = W4[c2*8+j][n]
        int j = i2 & 7, n = (i2 >> 3) & 511, c2 = i2 >> 12;
        int k = c2 * 8 + j;
        W4s[i2] = f2b(W4[k * 512 + n]);
    }
    int i3 = i - 172032;
    if (i3 >= 0 && i3 < 1024) {              // W1s[n*16+k] = W1[k][n] (k<3) else 0
        int k = i3 & 15, n = i3 >> 4;
        W1s[i3] = f2b(k < 3 ? W1[k * 64 + n] : 0.0f);
    }
    int i4 = i - 173056;
    if (i4 >= 0 && i4 < 8192) {              // W2s[n*64+k] = W2[k][n]
        int k = i4 & 63, n = i4 >> 6;
        W2s[i4] = f2b(W2[k * 128 + n]);
    }
}

// ======= sa1 (MFMA): block = 8 points as two sequential 4-point groups ======
// Per-group body is R8-proven; weight fragments hoisted (group-invariant).
__global__ __launch_bounds__(256) void sa1_kernel(
    const float* __restrict__ pos, const int* __restrict__ nbr,
    const unsigned short* __restrict__ W1s, const float* __restrict__ b1,
    const unsigned short* __restrict__ W2s, const float* __restrict__ b2,
    unsigned short* __restrict__ x1b)
{
    __shared__ unsigned short A1d[64 * 16];   // 2 KB
    __shared__ unsigned short A2[64 * 72];    // 9 KB
    const int tid  = threadIdx.x;
    const int lane = tid & 63;
    const int wave = tid >> 6;
    const int l31  = lane & 31;
    const int h    = lane >> 5;

    // group-invariant weight fragments + biases (loaded once)
    const int c1 = (wave >> 1) * 32 + l31;
    const v8bf b1f = *(const v8bf*)(W1s + c1 * 16 + h * 8);
    const float b1v = b1[c1];
    v8bf B2[4];
    #pragma unroll
    for (int kc = 0; kc < 4; ++kc)
        B2[kc] = *(const v8bf*)(W2s + (wave * 32 + l31) * 64 + kc * 16 + h * 8);
    const float b2v = b2[wave * 32 + l31];

    #pragma unroll
    for (int g = 0; g < 2; ++g) {
        const int p0 = blockIdx.x * 8 + g * 4;
        __syncthreads();   // previous group's A2 reads done before restage
        if (tid < 64) {
            int r = tid;
            int j = nbr[p0 * KNB + r];
            int p = p0 + (r >> 4);
            v8bf z;
            #pragma unroll
            for (int i = 0; i < 8; ++i) z[i] = 0;
            v8bf dv = z;
            dv[0] = (short)f2b(pos[j * 3 + 0] - pos[p * 3 + 0]);
            dv[1] = (short)f2b(pos[j * 3 + 1] - pos[p * 3 + 1]);
            dv[2] = (short)f2b(pos[j * 3 + 2] - pos[p * 3 + 2]);
            *(v8bf*)(A1d + r * 16)     = dv;
            *(v8bf*)(A1d + r * 16 + 8) = z;
        }
        __syncthreads();

        {
            v8bf a = *(const v8bf*)(A1d + ((wave & 1) * 32 + l31) * 16 + h * 8);
            v16f acc = __builtin_amdgcn_mfma_f32_32x32x16_bf16(a, b1f, zero16(), 0, 0, 0);
            #pragma unroll
            for (int r = 0; r < 16; ++r) {
                int row = (wave & 1) * 32 + (r & 3) + 8 * (r >> 2) + 4 * h;
                A2[row * 72 + c1] = f2b(fmaxf(acc[r] + b1v, 0.0f));
            }
        }
        __syncthreads();

        #pragma unroll
        for (int rt = 0; rt < 2; ++rt) {
            v16f acc = zero16();
            #pragma unroll
            for (int kc = 0; kc < 4; ++kc) {
                v8bf a = *(const v8bf*)(A2 + (rt * 32 + l31) * 72 + kc * 16 + h * 8);
                acc = __builtin_amdgcn_mfma_f32_32x32x16_bf16(a, B2[kc], acc, 0, 0, 0);
            }
            float ma = acc[0], mb = acc[8];
            #pragma unroll
            for (int r = 1; r < 8; ++r) { ma = fmaxf(ma, acc[r]); mb = fmaxf(mb, acc[8 + r]); }
            ma = fmaxf(ma, __shfl_xor(ma, 32));
            mb = fmaxf(mb, __shfl_xor(mb, 32));
            int p = p0 + rt * 2 + h;
            float m = h ? mb : ma;
            x1b[p * 128 + wave * 32 + l31] = f2b(m + b2v);
        }
    }
}

// ==== sa2 (MFMA): R8-proven — 8 points (M=128), 256 thr, padded A2 67.5 KB ==
__global__ __launch_bounds__(256) void sa2_kernel(
    const float* __restrict__ pos, const int* __restrict__ nbr,
    const int* __restrict__ batch,
    const unsigned short* __restrict__ W3s, const float* __restrict__ b3,
    const unsigned short* __restrict__ W4s, const float* __restrict__ b4,
    const unsigned short* __restrict__ x1b, unsigned* __restrict__ encbuf)
{
    __shared__ unsigned short S[128 * A2S];   // 67584 B: A1 (stride A1S) overlaid
    const int tid  = threadIdx.x;
    const int lane = tid & 63;
    const int wave = tid >> 6;
    const int l31  = lane & 31;
    const int h    = lane >> 5;
    const int p0   = blockIdx.x * 8;

    const float b3v0 = b3[(wave * 2 + 0) * 32 + l31];
    const float b3v1 = b3[(wave * 2 + 1) * 32 + l31];

    // ---- stage A1: 128 rows = (point, nbr); 2 threads/row, 128 B each
    {
        int r = tid >> 1, q = tid & 1;
        int j = nbr[p0 * KNB + r];
        const uint4* src = (const uint4*)(x1b + j * 128 + q * 64);
        uint4* dst = (uint4*)(S + r * A1S + q * 64);
        #pragma unroll
        for (int i = 0; i < 8; ++i) dst[i] = src[i];
    }
    if (tid < 128) {
        int r = tid;
        int j = nbr[p0 * KNB + r];
        int p = p0 + (r >> 4);
        v8bf z;
        #pragma unroll
        for (int i = 0; i < 8; ++i) z[i] = 0;
        v8bf dv = z;
        dv[0] = (short)f2b(pos[j * 3 + 0] - pos[p * 3 + 0]);
        dv[1] = (short)f2b(pos[j * 3 + 1] - pos[p * 3 + 1]);
        dv[2] = (short)f2b(pos[j * 3 + 2] - pos[p * 3 + 2]);
        *(v8bf*)(S + r * A1S + 128) = dv;
        *(v8bf*)(S + r * A1S + 136) = z;
    }
    __syncthreads();

    // ---- GEMM1: kc-streamed B, looped over 2 row-tile-pairs; kc=9 pad skipped
    const int n1a = (wave * 2 + 0) * 32 + l31;
    const int n1b = (wave * 2 + 1) * 32 + l31;
    unsigned stA[2][16], stB[2][16];   // [rtp][..] ci=0 / ci=1
    #pragma unroll
    for (int rtp = 0; rtp < 2; ++rtp) {
        v16f g00 = zero16(), g01 = zero16(), g10 = zero16(), g11 = zero16();
        #pragma unroll
        for (int kc = 0; kc < 9; ++kc) {
            v8bf a0 = *(const v8bf*)(S + (rtp * 64 + l31)      * A1S + kc * 16 + h * 8);
            v8bf a1 = *(const v8bf*)(S + (rtp * 64 + 32 + l31) * A1S + kc * 16 + h * 8);
            int c2 = kc * 2 + h;
            v8bf B0 = *(const v8bf*)(W3s + ((c2 * 256 + n1a) << 3));
            v8bf B1 = *(const v8bf*)(W3s + ((c2 * 256 + n1b) << 3));
            g00 = __builtin_amdgcn_mfma_f32_32x32x16_bf16(a0, B0, g00, 0, 0, 0);
            g10 = __builtin_amdgcn_mfma_f32_32x32x16_bf16(a1, B0, g10, 0, 0, 0);
            g01 = __builtin_amdgcn_mfma_f32_32x32x16_bf16(a0, B1, g01, 0, 0, 0);
            g11 = __builtin_amdgcn_mfma_f32_32x32x16_bf16(a1, B1, g11, 0, 0, 0);
        }
        #pragma unroll
        for (int i = 0; i < 8; ++i) {
            stA[rtp][i]     = pk2(fmaxf(g00[2*i] + b3v0, 0.0f), fmaxf(g00[2*i+1] + b3v0, 0.0f));
            stA[rtp][8 + i] = pk2(fmaxf(g10[2*i] + b3v0, 0.0f), fmaxf(g10[2*i+1] + b3v0, 0.0f));
            stB[rtp][i]     = pk2(fmaxf(g01[2*i] + b3v1, 0.0f), fmaxf(g01[2*i+1] + b3v1, 0.0f));
            stB[rtp][8 + i] = pk2(fmaxf(g11[2*i] + b3v1, 0.0f), fmaxf(g11[2*i+1] + b3v1, 0.0f));
        }
    }
    __syncthreads();   // all A1 reads complete — safe to overwrite with A2

    // ---- store A2 = bf16(relu(GEMM1)) row-major, stride A2S
    {
        const int c0 = (wave * 2 + 0) * 32 + l31;
        const int c1 = (wave * 2 + 1) * 32 + l31;
        #pragma unroll
        for (int rtp = 0; rtp < 2; ++rtp) {
            const int rb = rtp * 64;
            #pragma unroll
            for (int i = 0; i < 8; ++i) {
                int row = rb + ((2*i) & 3) + 8 * ((2*i) >> 2) + 4 * h;
                S[row * A2S + c0]        = (unsigned short)(stA[rtp][i] & 0xFFFF);
                S[(row + 1) * A2S + c0]  = (unsigned short)(stA[rtp][i] >> 16);
                S[(row + 32) * A2S + c0] = (unsigned short)(stA[rtp][8 + i] & 0xFFFF);
                S[(row + 33) * A2S + c0] = (unsigned short)(stA[rtp][8 + i] >> 16);
                S[row * A2S + c1]        = (unsigned short)(stB[rtp][i] & 0xFFFF);
                S[(row + 1) * A2S + c1]  = (unsigned short)(stB[rtp][i] >> 16);
                S[(row + 32) * A2S + c1] = (unsigned short)(stB[rtp][8 + i] & 0xFFFF);
                S[(row + 33) * A2S + c1] = (unsigned short)(stB[rtp][8 + i] >> 16);
            }
        }
    }
    __syncthreads();   // A2 ready

    // ---- GEMM2: ct-pair outer (B held, reused by both row-tile-pairs)
    const int cloud = batch[p0];
    #pragma unroll
    for (int cp = 0; cp < 2; ++cp) {
        const int ct0 = wave * 4 + cp * 2;
        const int n0 = ct0 * 32 + l31;
        const int n1 = (ct0 + 1) * 32 + l31;
        v8bf B2a[16], B2b[16];
        #pragma unroll
        for (int kc = 0; kc < 16; ++kc) {
            int c2 = kc * 2 + h;
            B2a[kc] = *(const v8bf*)(W4s + ((c2 * 512 + n0) << 3));
            B2b[kc] = *(const v8bf*)(W4s + ((c2 * 512 + n1) << 3));
        }
        float rm0 = -3.4e38f, rm1 = -3.4e38f;
        #pragma unroll
        for (int rtp = 0; rtp < 2; ++rtp) {
            v16f a00 = zero16(), a01 = zero16(), a10 = zero16(), a11 = zero16();
            #pragma unroll
            for (int kc = 0; kc < 16; ++kc) {
                v8bf a0 = *(const v8bf*)(S + (rtp * 64 + l31)      * A2S + kc * 16 + h * 8);
                v8bf a1 = *(const v8bf*)(S + (rtp * 64 + 32 + l31) * A2S + kc * 16 + h * 8);
                a00 = __builtin_amdgcn_mfma_f32_32x32x16_bf16(a0, B2a[kc], a00, 0, 0, 0);
                a10 = __builtin_amdgcn_mfma_f32_32x32x16_bf16(a1, B2a[kc], a10, 0, 0, 0);
                a01 = __builtin_amdgcn_mfma_f32_32x32x16_bf16(a0, B2b[kc], a01, 0, 0, 0);
                a11 = __builtin_amdgcn_mfma_f32_32x32x16_bf16(a1, B2b[kc], a11, 0, 0, 0);
            }
            #pragma unroll
            for (int r = 0; r < 16; ++r) {
                rm0 = fmaxf(rm0, fmaxf(a00[r], a10[r]));
                rm1 = fmaxf(rm1, fmaxf(a01[r], a11[r]));
            }
        }
        rm0 = fmaxf(rm0, __shfl_xor(rm0, 32));
        rm1 = fmaxf(rm1, __shfl_xor(rm1, 32));
        rm0 += b4[ct0 * 32 + l31];
        rm1 += b4[(ct0 + 1) * 32 + l31];
        if (lane < 32) {
            atomicMax(&encbuf[cloud * OUTC + ct0 * 32 + l31], fenc(rm0));
            atomicMax(&encbuf[cloud * OUTC + (ct0 + 1) * 32 + l31], fenc(rm1));
        }
    }
}

// ============================ finalize: decode encoded maxima ================
__global__ void finalize_kernel(const unsigned* __restrict__ encv,
                                float* __restrict__ out)
{
    int i = blockIdx.x * 256 + threadIdx.x;
    if (i < NCLOUD * OUTC) out[i] = fdec(encv[i]);
}

extern "C" void kernel_launch(void* const* d_in, const int* in_sizes, int n_in,
                              void* d_out, int out_size, void* d_ws, size_t ws_size,
                              hipStream_t stream)
{
    const float* pos   = (const float*)d_in[0];
    const int*   nbr   = (const int*)  d_in[1];
    const int*   batch = (const int*)  d_in[2];
    const float* W1    = (const float*)d_in[3];
    const float* b1    = (const float*)d_in[4];
    const float* W2    = (const float*)d_in[5];
    const float* b2    = (const float*)d_in[6];
    const float* W3    = (const float*)d_in[7];
    const float* b3    = (const float*)d_in[8];
    const float* W4    = (const float*)d_in[9];
    const float* b4    = (const float*)d_in[10];

    unsigned short* x1b = (unsigned short*)d_ws;                          // 8 MB
    unsigned short* W3s = (unsigned short*)((char*)d_ws + 8388608);       // 80 KB
    unsigned short* W4s = (unsigned short*)((char*)d_ws + 8470528);       // 256 KB
    unsigned*    encbuf = (unsigned*)((char*)d_ws + 8732672);             // 32 KB
    unsigned short* W1s = (unsigned short*)((char*)d_ws + 8765440);       // 2 KB
    unsigned short* W2s = (unsigned short*)((char*)d_ws + 8767488);       // 16 KB

    prep_kernel<<<708, 256, 0, stream>>>(W1, W2, W3, W4, W1s, W2s, W3s, W4s, encbuf);
    sa1_kernel<<<PTOT / 8, 256, 0, stream>>>(pos, nbr, W1s, b1, W2s, b2, x1b);
    sa2_kernel<<<PTOT / 8, 256, 0, stream>>>(pos, nbr, batch, W3s, b3, W4s, b4, x1b, encbuf);
    finalize_kernel<<<(NCLOUD * OUTC + 255) / 256, 256, 0, stream>>>(encbuf, (float*)d_out);
}